// Round 9
// baseline (268.414 us; speedup 1.0000x reference)
//
#include <hip/hip_runtime.h>
#include <cstdint>
#include <cstddef>

#define DEV __device__ __forceinline__

typedef float v2f __attribute__((ext_vector_type(2)));

DEV float fsig(float x)  { return __builtin_amdgcn_rcpf(1.0f + __expf(-x)); }
DEV float ftanh_(float x){ return 1.0f - 2.0f * __builtin_amdgcn_rcpf(1.0f + __expf(2.0f * x)); }
DEV float readlanef(float v, int l) {
    return __uint_as_float(__builtin_amdgcn_readlane(__float_as_uint(v), l));
}

// ---------------- ws layout (float offsets) ----------------
constexpr size_t ACC   = 0;                 // 64  (2 tracks x (16 sum + 16 sumsq))
constexpr size_t LO    = 128;               // 65536  Lo[64][128][8]
constexpr size_t RO    = LO + 65536;        // 65536  Ro[64][128][8]
constexpr size_t HBUF  = RO + 65536;        // 262144 h[track][8192][16]
constexpr size_t ZLAST = HBUF + 262144;     // 1024   zlast[64][16]

// ===== K1: gate GRU, 1 seq/wave, skewed layers, readlane + pk(r,z) =====
__global__ __launch_bounds__(64, 1) void k1_gate(
    const float* __restrict__ Local, const float* __restrict__ Remote,
    const float* __restrict__ Wih0, const float* __restrict__ Whh0,
    const float* __restrict__ bih0, const float* __restrict__ bhh0,
    const float* __restrict__ Wih1, const float* __restrict__ Whh1,
    const float* __restrict__ bih1, const float* __restrict__ bhh1,
    float* __restrict__ ws)
{
    const int tid = threadIdx.x;
    const int j = tid & 7;
    const int layer = (tid >> 3) & 1;
    const int blk = blockIdx.x;
    const int track = blk >> 6;
    const int b = blk & 63;
    if (blk == 0) ws[ACC + tid] = 0.f;

    __shared__ float xwg[128][24];     // precomputed bih0 + Wih0 . x(t)
    __shared__ float h1all[128][9];

    const float* __restrict__ src = track ? Remote : Local;
    for (int t = tid; t < 128; t += 64) {
        const float* p = src + ((size_t)b * 128 + t) * 132 + 128;
        float x0 = p[0], x1 = p[1], x2 = p[2];
#pragma unroll
        for (int u = 0; u < 24; ++u) {
            float a = bih0[u];
            a = fmaf(Wih0[u * 3 + 0], x0, a);
            a = fmaf(Wih0[u * 3 + 1], x1, a);
            a = fmaf(Wih0[u * 3 + 2], x2, a);
            xwg[t][u] = a;
        }
    }

    const float* __restrict__ Wsel = layer ? Wih1 : Whh0;
    const float mhi = layer ? 1.f : 0.f;
    const float m0f = layer ? 0.f : 1.f;

    // named weight registers: lo = Wsel (h0-or-x side), hi = mhi*Whh1 (h1 side)
    v2f wrz0, wrz1, wrz2, wrz3, wrz4, wrz5, wrz6, wrz7;
    v2f wrzh0, wrzh1, wrzh2, wrzh3, wrzh4, wrzh5, wrzh6, wrzh7;
    float wc0, wc1, wc2, wc3, wc4, wc5, wc6, wc7;
    float wch0, wch1, wch2, wch3, wch4, wch5, wch6, wch7;
#define K1_INIT(n) \
    wrz##n  = (v2f){ Wsel[j * 8 + (n)], Wsel[(8 + j) * 8 + (n)] }; \
    wc##n   = Wsel[(16 + j) * 8 + (n)]; \
    wrzh##n = (v2f){ mhi * Whh1[j * 8 + (n)], mhi * Whh1[(8 + j) * 8 + (n)] }; \
    wch##n  = mhi * Whh1[(16 + j) * 8 + (n)];
    K1_INIT(0) K1_INIT(1) K1_INIT(2) K1_INIT(3)
    K1_INIT(4) K1_INIT(5) K1_INIT(6) K1_INIT(7)
#undef K1_INIT

    const float base_r  = layer ? (bih1[j] + bhh1[j])         : bhh0[j];
    const float base_z  = layer ? (bih1[8 + j] + bhh1[8 + j]) : bhh0[8 + j];
    const float base_in = layer ? bih1[16 + j]                : 0.f;
    const float base_dn = layer ? bhh1[16 + j]                : bhh0[16 + j];
    __syncthreads();   // once: xwg staged

    float hown = 0.f;
    float p0 = xwg[0][j], p1 = xwg[0][8 + j], p2 = xwg[0][16 + j];
#pragma unroll 1
    for (int t = 0; t <= 128; ++t) {
        int tn = t < 127 ? t + 1 : 127;
        float q0 = xwg[tn][j], q1 = xwg[tn][8 + j], q2 = xwg[tn][16 + j];
        v2f aR0 = (v2f){0.f, 0.f}, aR1 = (v2f){0.f, 0.f};
        v2f aH0 = (v2f){0.f, 0.f}, aH1 = (v2f){0.f, 0.f};
        float cL0 = 0.f, cL1 = 0.f, cH0 = 0.f, cH1 = 0.f;
#define K1_LO(n, c) { float bb = readlanef(hown, (n)); \
        aR##c += wrz##n * bb; cL##c = fmaf(wc##n, bb, cL##c); }
#define K1_HI(n, c) { float bb = readlanef(hown, 8 + (n)); \
        aH##c += wrzh##n * bb; cH##c = fmaf(wch##n, bb, cH##c); }
        K1_LO(0, 0) K1_HI(0, 0) K1_LO(1, 1) K1_HI(1, 1)
        K1_LO(2, 0) K1_HI(2, 0) K1_LO(3, 1) K1_HI(3, 1)
        K1_LO(4, 0) K1_HI(4, 0) K1_LO(5, 1) K1_HI(5, 1)
        K1_LO(6, 0) K1_HI(6, 0) K1_LO(7, 1) K1_HI(7, 1)
#undef K1_LO
#undef K1_HI
        v2f aT = aR0 + aR1 + aH0 + aH1;
        float cLo = cL0 + cL1, cHi = cH0 + cH1;
        float ar = base_r + fmaf(m0f, p0, aT.x);
        float az = base_z + fmaf(m0f, p1, aT.y);
        float in_ = layer ? (base_in + cLo) : p2;
        float dn  = base_dn + (layer ? cHi : cLo);
        float r = fsig(ar);
        float z = fsig(az);
        float n = ftanh_(in_ + r * dn);
        float hnew = n + z * (hown - n);
        bool act = layer ? (t >= 1) : (t < 128);
        hown = act ? hnew : hown;
        if (tid >= 8 && tid < 16 && t >= 1) h1all[t - 1][j] = hown;
        p0 = q0; p1 = q1; p2 = q2;
    }
    __syncthreads();

    // softmax over layer-1 outputs
    float* __restrict__ outp = ws + (track ? RO : LO);
    for (int t = tid; t < 128; t += 64) {
        float vv[8];
#pragma unroll
        for (int k = 0; k < 8; ++k) vv[k] = h1all[t][k];
        float mx = vv[0];
#pragma unroll
        for (int k = 1; k < 8; ++k) mx = fmaxf(mx, vv[k]);
        float ssum = 0.f;
#pragma unroll
        for (int k = 0; k < 8; ++k) { vv[k] = __expf(vv[k] - mx); ssum += vv[k]; }
        float inv = __builtin_amdgcn_rcpf(ssum);
        size_t base = ((size_t)b * 128 + t) * 8;
        float4 o0 = make_float4(vv[0] * inv, vv[1] * inv, vv[2] * inv, vv[3] * inv);
        float4 o1 = make_float4(vv[4] * inv, vv[5] * inv, vv[6] * inv, vv[7] * inv);
        *(float4*)(outp + base) = o0;
        *(float4*)(outp + base + 4) = o1;
    }
}

// ====== K2: expert layer-1 GEMM + gate mix + batch-stat accumulation ======
__global__ __launch_bounds__(256) void k2_expert1(
    const float* __restrict__ Local, const float* __restrict__ Remote,
    const float* __restrict__ ae_w1, const float* __restrict__ ae_b1,
    float* __restrict__ ws)
{
    const int blk = blockIdx.x;
    const int track = blk >> 7;
    const int n0 = (blk & 127) * 64;
    const float* __restrict__ X = track ? Remote : Local;
    const float* __restrict__ om = ws + (track ? RO : LO);

    __shared__ __align__(16) float xsh[64 * 132];
    __shared__ __align__(16) float wsh[16 * 1040];
    __shared__ float omsh[64][8];
    __shared__ float b1sh[128];
    __shared__ float red[32];
    const int tid = threadIdx.x;

    for (int i = tid; i < 2048; i += 256) {
        int r = i >> 5, q = i & 31;
        ((float4*)&xsh[r * 132])[q] = ((const float4*)(X + (size_t)(n0 + r) * 132))[q];
    }
    for (int i4 = tid; i4 < 4096; i4 += 256) {
        float4 v = ((const float4*)ae_w1)[i4];
        int i = i4 * 4;
#pragma unroll
        for (int c = 0; c < 4; ++c) {
            int ii = i + c;
            int h = ii & 15, kk = (ii >> 4) & 127, e = ii >> 11;
            float vc = c == 0 ? v.x : c == 1 ? v.y : c == 2 ? v.z : v.w;
            wsh[h * 1040 + e * 130 + kk] = vc;
        }
    }
    for (int i = tid; i < 512; i += 256) omsh[i >> 3][i & 7] = om[(size_t)(n0 + (i >> 3)) * 8 + (i & 7)];
    for (int i = tid; i < 128; i += 256) b1sh[i] = ae_b1[i];
    if (tid < 32) red[tid] = 0.f;
    __syncthreads();

    const int hh = tid & 15, rg = tid >> 4;
    float acc[4][8];
#pragma unroll
    for (int r = 0; r < 4; ++r)
#pragma unroll
        for (int e = 0; e < 8; ++e) acc[r][e] = 0.f;

#pragma unroll 4
    for (int kq = 0; kq < 32; ++kq) {
        float4 xv[4], wv[8];
#pragma unroll
        for (int r = 0; r < 4; ++r) xv[r] = *(const float4*)&xsh[(rg * 4 + r) * 132 + kq * 4];
#pragma unroll
        for (int e = 0; e < 8; ++e) wv[e] = *(const float4*)&wsh[hh * 1040 + e * 130 + kq * 4];
#pragma unroll
        for (int r = 0; r < 4; ++r)
#pragma unroll
            for (int e = 0; e < 8; ++e) {
                float a = acc[r][e];
                a = fmaf(xv[r].x, wv[e].x, a);
                a = fmaf(xv[r].y, wv[e].y, a);
                a = fmaf(xv[r].z, wv[e].z, a);
                a = fmaf(xv[r].w, wv[e].w, a);
                acc[r][e] = a;
            }
    }

    float s = 0.f, s2 = 0.f;
    float* __restrict__ hout = ws + HBUF + (size_t)track * 131072;
#pragma unroll
    for (int r = 0; r < 4; ++r) {
        int row = rg * 4 + r;
        float hv = 0.f;
#pragma unroll
        for (int e = 0; e < 8; ++e) hv = fmaf(omsh[row][e], acc[r][e] + b1sh[e * 16 + hh], hv);
        hout[(size_t)(n0 + row) * 16 + hh] = hv;
        s += hv; s2 += hv * hv;
    }
    __syncthreads();
    atomicAdd(&red[hh], s);
    atomicAdd(&red[16 + hh], s2);
    __syncthreads();
    if (tid < 32) atomicAdd(&ws[ACC + track * 32 + tid], red[tid]);
}

// ===== K34: phase A (BN+ELU+MLP2+xw0+Whh1 staging) then phase B recurrence =====
__global__ __launch_bounds__(256, 1) void k34_fused(
    const float* __restrict__ ae_w2, const float* __restrict__ ae_b2,
    const float* __restrict__ ae_g, const float* __restrict__ ae_bt,
    const float* __restrict__ mWih0, const float* __restrict__ mbih0,
    const float* __restrict__ Whh0, const float* __restrict__ bhh0,
    const float* __restrict__ Wih1, const float* __restrict__ Whh1,
    const float* __restrict__ bih1, const float* __restrict__ bhh1,
    float* __restrict__ ws)
{
    const int s = blockIdx.x;           // sequence 0..63
    const int tid = threadIdx.x;

    __shared__ float stat[4][16];
    __shared__ float omsh[2][128][8];
    __shared__ float w2sh[2048];
    __shared__ float b2sh[128];
    __shared__ float actsh[2][128][16];
    __shared__ float zsh[128][17];
    __shared__ float wihsh[48][17];
    __shared__ float bihsh[48];
    __shared__ float xwsh[128 * 48];
    __shared__ __align__(16) float whh1sh[16 * 52];  // [j][ {rz pairs k<16}(32) | {c k<16}(16) ], stride 52

    // ---- phase A ----
    if (tid < 32) {
        int trk = tid >> 4, h = tid & 15;
        float sm = ws[ACC + trk * 32 + h], s2 = ws[ACC + trk * 32 + 16 + h];
        float m = sm * (1.f / 8192.f);
        float v = fmaxf(s2 * (1.f / 8192.f) - m * m, 0.f);
        stat[trk * 2][h] = m;
        stat[trk * 2 + 1][h] = rsqrtf(v + 1e-5f);
    }
    for (int i = tid; i < 2048; i += 256) w2sh[i] = ae_w2[i];
    for (int i = tid; i < 128; i += 256) b2sh[i] = ae_b2[i];
    for (int i = tid; i < 768; i += 256) wihsh[i >> 4][i & 15] = mWih0[i];
    if (tid < 48) bihsh[tid] = mbih0[tid];
    // stage Whh1 -> LDS: rz interleaved pairs then c
    for (int i = tid; i < 768; i += 256) {
        int jj = i / 48, c = i - jj * 48;
        float v;
        if (c < 32) { int k = c >> 1, g = c & 1; v = Whh1[((size_t)(g * 16 + jj)) * 16 + k]; }
        else        { int k = c - 32;            v = Whh1[((size_t)(32 + jj)) * 16 + k]; }
        whh1sh[jj * 52 + c] = v;
    }
    for (int i = tid; i < 2048; i += 256) {
        int trk = i >> 10, r = (i >> 3) & 127, e = i & 7;
        omsh[trk][r][e] = ws[(trk ? RO : LO) + ((size_t)s * 128 + r) * 8 + e];
    }
    __syncthreads();

    for (int i = tid; i < 4096; i += 256) {
        int trk = i >> 11, r = (i >> 4) & 127, h = i & 15;
        float v = ws[HBUF + (size_t)trk * 131072 + ((size_t)s * 128 + r) * 16 + h];
        float a = ae_g[h] * (v - stat[trk * 2][h]) * stat[trk * 2 + 1][h] + ae_bt[h];
        actsh[trk][r][h] = a > 0.f ? a : expm1f(a);
    }
    __syncthreads();

    for (int i = tid; i < 2048; i += 256) {
        int r = i >> 4, o = i & 15;
        float accv = 0.f;
#pragma unroll
        for (int trk = 0; trk < 2; ++trk) {
#pragma unroll
            for (int e = 0; e < 8; ++e) {
                const float* w = &w2sh[e * 256 + o];
                float t = b2sh[e * 16 + o];
#pragma unroll
                for (int h = 0; h < 16; ++h) t = fmaf(actsh[trk][r][h], w[h * 16], t);
                accv = fmaf(omsh[trk][r][e], t, accv);
            }
        }
        zsh[r][o] = accv;
    }
    __syncthreads();

    for (int i = tid; i < 6144; i += 256) {
        int r = i / 48, g = i - r * 48;
        float a = bihsh[g];
#pragma unroll
        for (int k = 0; k < 16; ++k) a = fmaf(zsh[r][k], wihsh[g][k], a);
        xwsh[r * 48 + g] = a;
    }
    __syncthreads();

    // ---- phase B: recurrence, wave 0 only ----
    if (tid >= 64) return;

    const int j = tid & 15;
    const int layer = (tid >> 4) & 1;

    const float* __restrict__ Wsel = layer ? Wih1 : Whh0;
    const float m0f = layer ? 0.f : 1.f;
    // reg weights: 16 slots over vb[0..15] (h0 side for both layers)
    v2f wrz0, wrz1, wrz2, wrz3, wrz4, wrz5, wrz6, wrz7;
    v2f wrz8, wrz9, wrz10, wrz11, wrz12, wrz13, wrz14, wrz15;
    float wc0, wc1, wc2, wc3, wc4, wc5, wc6, wc7;
    float wc8, wc9, wc10, wc11, wc12, wc13, wc14, wc15;
#define K34_INIT(n) \
    wrz##n = (v2f){ Wsel[j * 16 + (n)], Wsel[(16 + j) * 16 + (n)] }; \
    wc##n  = Wsel[(32 + j) * 16 + (n)];
    K34_INIT(0) K34_INIT(1) K34_INIT(2) K34_INIT(3)
    K34_INIT(4) K34_INIT(5) K34_INIT(6) K34_INIT(7)
    K34_INIT(8) K34_INIT(9) K34_INIT(10) K34_INIT(11)
    K34_INIT(12) K34_INIT(13) K34_INIT(14) K34_INIT(15)
#undef K34_INIT

    const float base_r  = layer ? (bih1[j] + bhh1[j])           : bhh0[j];
    const float base_z  = layer ? (bih1[16 + j] + bhh1[16 + j]) : bhh0[16 + j];
    const float base_in = layer ? bih1[32 + j]                  : 0.f;
    const float base_dn = layer ? bhh1[32 + j]                  : bhh0[32 + j];

    const float4* __restrict__ wl4 = (const float4*)&whh1sh[j * 52];

    float hown = 0.f;
    float p0 = xwsh[j], p1 = xwsh[16 + j], p2 = xwsh[32 + j];
#pragma unroll 1
    for (int t = 0; t <= 128; ++t) {
        int tn = (t < 127 ? t + 1 : 127) * 48;
        float q0 = xwsh[tn + j], q1 = xwsh[tn + 16 + j], q2 = xwsh[tn + 32 + j];
        // LDS h-side weights (loop-invariant addresses -> issued early)
        float4 f0 = wl4[0], f1 = wl4[1], f2 = wl4[2], f3 = wl4[3];
        float4 f4 = wl4[4], f5 = wl4[5], f6 = wl4[6], f7 = wl4[7];
        float4 g0 = wl4[8], g1 = wl4[9], g2 = wl4[10], g3 = wl4[11];
        v2f aR0 = (v2f){0.f, 0.f}, aR1 = (v2f){0.f, 0.f};
        v2f aL0 = (v2f){0.f, 0.f}, aL1 = (v2f){0.f, 0.f};
        float cR0 = 0.f, cR1 = 0.f, cL0 = 0.f, cL1 = 0.f;
#define K34_REG(n, c) { float bb = readlanef(hown, (n)); \
        aR##c += wrz##n * bb; cR##c = fmaf(wc##n, bb, cR##c); }
#define K34_LDS(n, c, px, py, wcv) { float bb = readlanef(hown, 16 + (n)); \
        aL##c += ((v2f){(px), (py)}) * bb; cL##c = fmaf((wcv), bb, cL##c); }
        K34_REG(0, 0)  K34_LDS(0, 0, f0.x, f0.y, g0.x)
        K34_REG(1, 1)  K34_LDS(1, 1, f0.z, f0.w, g0.y)
        K34_REG(2, 0)  K34_LDS(2, 0, f1.x, f1.y, g0.z)
        K34_REG(3, 1)  K34_LDS(3, 1, f1.z, f1.w, g0.w)
        K34_REG(4, 0)  K34_LDS(4, 0, f2.x, f2.y, g1.x)
        K34_REG(5, 1)  K34_LDS(5, 1, f2.z, f2.w, g1.y)
        K34_REG(6, 0)  K34_LDS(6, 0, f3.x, f3.y, g1.z)
        K34_REG(7, 1)  K34_LDS(7, 1, f3.z, f3.w, g1.w)
        K34_REG(8, 0)  K34_LDS(8, 0, f4.x, f4.y, g2.x)
        K34_REG(9, 1)  K34_LDS(9, 1, f4.z, f4.w, g2.y)
        K34_REG(10, 0) K34_LDS(10, 0, f5.x, f5.y, g2.z)
        K34_REG(11, 1) K34_LDS(11, 1, f5.z, f5.w, g2.w)
        K34_REG(12, 0) K34_LDS(12, 0, f6.x, f6.y, g3.x)
        K34_REG(13, 1) K34_LDS(13, 1, f6.z, f6.w, g3.y)
        K34_REG(14, 0) K34_LDS(14, 0, f7.x, f7.y, g3.z)
        K34_REG(15, 1) K34_LDS(15, 1, f7.z, f7.w, g3.w)
#undef K34_REG
#undef K34_LDS
        v2f aR = aR0 + aR1, aL = aL0 + aL1;
        float cR = cR0 + cR1, cL = cL0 + cL1;
        float ar = base_r + aR.x + (layer ? aL.x : p0);
        float az = base_z + aR.y + (layer ? aL.y : p1);
        float in_ = layer ? (base_in + cR) : p2;
        float dn  = base_dn + (layer ? cL : cR);
        float r = fsig(ar);
        float z = fsig(az);
        float n = ftanh_(in_ + r * dn);
        float hnew = n + z * (hown - n);
        bool act = layer ? (t >= 1) : (t < 128);
        hown = act ? hnew : hown;
        p0 = q0; p1 = q1; p2 = q2;
    }
    if (tid >= 16 && tid < 32) ws[ZLAST + (size_t)s * 16 + j] = hown;
}

// ===== K5: decoder MLP fused (layer1+BN redundant per block, layer2 slice) =====
__global__ __launch_bounds__(256) void k5_dec(
    const float* __restrict__ Remote,
    const float* __restrict__ md_w1, const float* __restrict__ md_b1,
    const float* __restrict__ md_g, const float* __restrict__ md_bt,
    const float* __restrict__ md_w2, const float* __restrict__ md_b2,
    const float* __restrict__ ws, float* __restrict__ out)
{
    const int o0 = blockIdx.x * 8;
    const int tid = threadIdx.x;
    __shared__ float xsh[64][17];
    __shared__ float omsh[64][8];
    __shared__ float w1sh[2176];
    __shared__ float b1sh[128];
    __shared__ float hsh[64][17];
    __shared__ float ssum[16], ss2[16], mstat[2][16];
    __shared__ float ash[64][17];
    __shared__ float w2sh[8][16][8];
    __shared__ float b2sh[8][8];

    for (int i = tid; i < 1024; i += 256) xsh[i >> 4][i & 15] = ws[ZLAST + i];
    if (tid < 64) xsh[tid][16] = Remote[((size_t)tid * 128 + 127) * 132 + 131];
    for (int i = tid; i < 512; i += 256)
        omsh[i >> 3][i & 7] = ws[RO + ((size_t)(i >> 3) * 128 + 127) * 8 + (i & 7)];
    for (int i = tid; i < 2176; i += 256) w1sh[i] = md_w1[i];
    for (int i = tid; i < 128; i += 256) b1sh[i] = md_b1[i];
    for (int i = tid; i < 1024; i += 256) {
        int e = i >> 7, h = (i >> 3) & 15, oo = i & 7;
        w2sh[e][h][oo] = md_w2[((size_t)e * 16 + h) * 128 + o0 + oo];
    }
    if (tid < 64) b2sh[tid >> 3][tid & 7] = md_b2[(size_t)(tid >> 3) * 128 + o0 + (tid & 7)];
    if (tid < 16) { ssum[tid] = 0.f; ss2[tid] = 0.f; }
    __syncthreads();

    for (int i = tid; i < 1024; i += 256) {
        int b = i >> 4, h = i & 15;
        float accv = 0.f;
#pragma unroll
        for (int e = 0; e < 8; ++e) {
            float t = b1sh[e * 16 + h];
            const float* w = &w1sh[e * 272 + h];
#pragma unroll
            for (int i2 = 0; i2 < 17; ++i2) t = fmaf(xsh[b][i2], w[i2 * 16], t);
            accv = fmaf(omsh[b][e], t, accv);
        }
        hsh[b][h] = accv;
        atomicAdd(&ssum[h], accv);
        atomicAdd(&ss2[h], accv * accv);
    }
    __syncthreads();
    if (tid < 16) {
        float m = ssum[tid] * (1.f / 64.f);
        float v = fmaxf(ss2[tid] * (1.f / 64.f) - m * m, 0.f);
        mstat[0][tid] = m;
        mstat[1][tid] = rsqrtf(v + 1e-5f);
    }
    __syncthreads();
    for (int i = tid; i < 1024; i += 256) {
        int b = i >> 4, h = i & 15;
        float a = md_g[h] * (hsh[b][h] - mstat[0][h]) * mstat[1][h] + md_bt[h];
        ash[b][h] = a > 0.f ? a : expm1f(a);
    }
    __syncthreads();

    for (int i = tid; i < 512; i += 256) {
        int b = i >> 3, oo = i & 7;
        float accv = 0.f;
#pragma unroll
        for (int e = 0; e < 8; ++e) {
            float t = b2sh[e][oo];
#pragma unroll
            for (int h = 0; h < 16; ++h) t = fmaf(ash[b][h], w2sh[e][h][oo], t);
            accv = fmaf(omsh[b][e], t, accv);
        }
        out[(size_t)b * 128 + o0 + oo] = accv;
    }
}

extern "C" void kernel_launch(void* const* d_in, const int* in_sizes, int n_in,
                              void* d_out, int out_size, void* d_ws, size_t ws_size,
                              hipStream_t stream) {
    const float* Local  = (const float*)d_in[0];
    const float* Remote = (const float*)d_in[1];
    const float* gWih0  = (const float*)d_in[2];
    const float* gWhh0  = (const float*)d_in[3];
    const float* gbih0  = (const float*)d_in[4];
    const float* gbhh0  = (const float*)d_in[5];
    const float* gWih1  = (const float*)d_in[6];
    const float* gWhh1  = (const float*)d_in[7];
    const float* gbih1  = (const float*)d_in[8];
    const float* gbhh1  = (const float*)d_in[9];
    const float* mWih0  = (const float*)d_in[10];
    const float* mWhh0  = (const float*)d_in[11];
    const float* mbih0  = (const float*)d_in[12];
    const float* mbhh0  = (const float*)d_in[13];
    const float* mWih1  = (const float*)d_in[14];
    const float* mWhh1  = (const float*)d_in[15];
    const float* mbih1  = (const float*)d_in[16];
    const float* mbhh1  = (const float*)d_in[17];
    const float* ae_w1  = (const float*)d_in[18];
    const float* ae_b1  = (const float*)d_in[19];
    const float* ae_w2  = (const float*)d_in[20];
    const float* ae_b2  = (const float*)d_in[21];
    const float* ae_g   = (const float*)d_in[22];
    const float* ae_bt  = (const float*)d_in[23];
    const float* md_w1  = (const float*)d_in[24];
    const float* md_b1  = (const float*)d_in[25];
    const float* md_w2  = (const float*)d_in[26];
    const float* md_b2  = (const float*)d_in[27];
    const float* md_g   = (const float*)d_in[28];
    const float* md_bt  = (const float*)d_in[29];
    float* ws  = (float*)d_ws;
    float* out = (float*)d_out;

    k1_gate<<<128, 64, 0, stream>>>(Local, Remote, gWih0, gWhh0, gbih0, gbhh0,
                                    gWih1, gWhh1, gbih1, gbhh1, ws);
    k2_expert1<<<256, 256, 0, stream>>>(Local, Remote, ae_w1, ae_b1, ws);
    k34_fused<<<64, 256, 0, stream>>>(ae_w2, ae_b2, ae_g, ae_bt, mWih0, mbih0,
                                      mWhh0, mbhh0, mWih1, mWhh1, mbih1, mbhh1, ws);
    k5_dec<<<16, 256, 0, stream>>>(Remote, md_w1, md_b1, md_g, md_bt,
                                   md_w2, md_b2, ws, out);
}

// Round 10
// 248.953 us; speedup vs baseline: 1.0782x; 1.0782x over previous
//
#include <hip/hip_runtime.h>
#include <cstdint>
#include <cstddef>

#define DEV __device__ __forceinline__

DEV float fsig(float x)  { return __builtin_amdgcn_rcpf(1.0f + __expf(-x)); }
DEV float ftanh_(float x){ return 1.0f - 2.0f * __builtin_amdgcn_rcpf(1.0f + __expf(2.0f * x)); }
DEV float readlanef(float v, int l) {
    return __uint_as_float(__builtin_amdgcn_readlane(__float_as_uint(v), l));
}

// Force values to be opaque register-resident (defeats load rematerialization
// inside the recurrence loop — the MachineLICM pressure heuristic otherwise
// leaves ~half the weight loads inside the 129-iteration loop; VGPR stuck at
// 104 across R5-R9 while the budget at 1 wave/EU is 512).
#define LAUNDER4(a,b,c,d) asm volatile("" : "+v"(a), "+v"(b), "+v"(c), "+v"(d))

// ---------------- ws layout (float offsets) ----------------
constexpr size_t ACC   = 0;                 // 64  (2 tracks x (16 sum + 16 sumsq))
constexpr size_t LO    = 128;               // 65536  Lo[64][128][8]
constexpr size_t RO    = LO + 65536;        // 65536  Ro[64][128][8]
constexpr size_t HBUF  = RO + 65536;        // 262144 h[track][8192][16]
constexpr size_t ZLAST = HBUF + 262144;     // 1024   zlast[64][16]

// ===== K1: gate GRU, 1 seq/wave, skewed layers, readlane broadcast =====
__global__ __launch_bounds__(64, 1) void k1_gate(
    const float* __restrict__ Local, const float* __restrict__ Remote,
    const float* __restrict__ Wih0, const float* __restrict__ Whh0,
    const float* __restrict__ bih0, const float* __restrict__ bhh0,
    const float* __restrict__ Wih1, const float* __restrict__ Whh1,
    const float* __restrict__ bih1, const float* __restrict__ bhh1,
    float* __restrict__ ws)
{
    const int tid = threadIdx.x;
    const int j = tid & 7;
    const int layer = (tid >> 3) & 1;
    const int blk = blockIdx.x;
    const int track = blk >> 6;
    const int b = blk & 63;
    if (blk == 0) ws[ACC + tid] = 0.f;

    __shared__ float xwg[128][24];     // precomputed bih0 + Wih0 . x(t)
    __shared__ float h1all[128][9];

    const float* __restrict__ src = track ? Remote : Local;
    for (int t = tid; t < 128; t += 64) {
        const float* p = src + ((size_t)b * 128 + t) * 132 + 128;
        float x0 = p[0], x1 = p[1], x2 = p[2];
#pragma unroll
        for (int u = 0; u < 24; ++u) {
            float a = bih0[u];
            a = fmaf(Wih0[u * 3 + 0], x0, a);
            a = fmaf(Wih0[u * 3 + 1], x1, a);
            a = fmaf(Wih0[u * 3 + 2], x2, a);
            xwg[t][u] = a;
        }
    }

    const float* __restrict__ Wsel = layer ? Wih1 : Whh0;
    const float mhi = layer ? 1.f : 0.f;
    const float m0f = layer ? 0.f : 1.f;

    // 48 named weight scalars: lo slots (h0 side) + hi slots (h1 side)
#define K1_WDECL(n) float wr##n, wz##n, wc##n, wrh##n, wzh##n, wch##n;
    K1_WDECL(0) K1_WDECL(1) K1_WDECL(2) K1_WDECL(3)
    K1_WDECL(4) K1_WDECL(5) K1_WDECL(6) K1_WDECL(7)
#undef K1_WDECL
#define K1_WINIT(n) \
    wr##n  = Wsel[j * 8 + (n)]; \
    wz##n  = Wsel[(8 + j) * 8 + (n)]; \
    wc##n  = Wsel[(16 + j) * 8 + (n)]; \
    wrh##n = mhi * Whh1[j * 8 + (n)]; \
    wzh##n = mhi * Whh1[(8 + j) * 8 + (n)]; \
    wch##n = mhi * Whh1[(16 + j) * 8 + (n)];
    K1_WINIT(0) K1_WINIT(1) K1_WINIT(2) K1_WINIT(3)
    K1_WINIT(4) K1_WINIT(5) K1_WINIT(6) K1_WINIT(7)
#undef K1_WINIT
#define K1_LND(n) LAUNDER4(wr##n, wz##n, wc##n, wrh##n); LAUNDER4(wzh##n, wch##n, wr##n, wz##n);
    K1_LND(0) K1_LND(1) K1_LND(2) K1_LND(3)
    K1_LND(4) K1_LND(5) K1_LND(6) K1_LND(7)
#undef K1_LND

    const float base_r  = layer ? (bih1[j] + bhh1[j])         : bhh0[j];
    const float base_z  = layer ? (bih1[8 + j] + bhh1[8 + j]) : bhh0[8 + j];
    const float base_in = layer ? bih1[16 + j]                : 0.f;
    const float base_dn = layer ? bhh1[16 + j]                : bhh0[16 + j];
    __syncthreads();   // once: xwg staged

    float hown = 0.f;
    float p0 = xwg[0][j], p1 = xwg[0][8 + j], p2 = xwg[0][16 + j];
#pragma unroll 1
    for (int t = 0; t <= 128; ++t) {
        int tn = t < 127 ? t + 1 : 127;
        float q0 = xwg[tn][j], q1 = xwg[tn][8 + j], q2 = xwg[tn][16 + j];
        float arA = 0.f, arB = 0.f, azA = 0.f, azB = 0.f;
        float acl0 = 0.f, acl1 = 0.f, ach0 = 0.f, ach1 = 0.f;
#define K1_STEP(n, A, C) { \
        float b0 = readlanef(hown, (n)); \
        ar##A = fmaf(wr##n, b0, ar##A); \
        az##A = fmaf(wz##n, b0, az##A); \
        acl##C = fmaf(wc##n, b0, acl##C); \
        float b1 = readlanef(hown, 8 + (n)); \
        ar##A = fmaf(wrh##n, b1, ar##A); \
        az##A = fmaf(wzh##n, b1, az##A); \
        ach##C = fmaf(wch##n, b1, ach##C); }
        K1_STEP(0, A, 0) K1_STEP(1, B, 1)
        K1_STEP(2, A, 0) K1_STEP(3, B, 1)
        K1_STEP(4, A, 0) K1_STEP(5, B, 1)
        K1_STEP(6, A, 0) K1_STEP(7, B, 1)
#undef K1_STEP
        float ac_lo = acl0 + acl1, ac_hi = ach0 + ach1;
        float ar = base_r + fmaf(m0f, p0, arA + arB);
        float az = base_z + fmaf(m0f, p1, azA + azB);
        float in_ = layer ? (base_in + ac_lo) : p2;
        float dn  = base_dn + (layer ? ac_hi : ac_lo);
        float r = fsig(ar);
        float z = fsig(az);
        float n = ftanh_(in_ + r * dn);
        float hnew = n + z * (hown - n);
        bool act = layer ? (t >= 1) : (t < 128);
        hown = act ? hnew : hown;
        if (tid >= 8 && tid < 16 && t >= 1) h1all[t - 1][j] = hown;
        p0 = q0; p1 = q1; p2 = q2;
    }
    __syncthreads();

    // softmax over layer-1 outputs
    float* __restrict__ outp = ws + (track ? RO : LO);
    for (int t = tid; t < 128; t += 64) {
        float vv[8];
#pragma unroll
        for (int k = 0; k < 8; ++k) vv[k] = h1all[t][k];
        float mx = vv[0];
#pragma unroll
        for (int k = 1; k < 8; ++k) mx = fmaxf(mx, vv[k]);
        float ssum = 0.f;
#pragma unroll
        for (int k = 0; k < 8; ++k) { vv[k] = __expf(vv[k] - mx); ssum += vv[k]; }
        float inv = __builtin_amdgcn_rcpf(ssum);
        size_t base = ((size_t)b * 128 + t) * 8;
        float4 o0 = make_float4(vv[0] * inv, vv[1] * inv, vv[2] * inv, vv[3] * inv);
        float4 o1 = make_float4(vv[4] * inv, vv[5] * inv, vv[6] * inv, vv[7] * inv);
        *(float4*)(outp + base) = o0;
        *(float4*)(outp + base + 4) = o1;
    }
}

// ====== K2: expert layer-1 GEMM + gate mix + batch-stat accumulation ======
__global__ __launch_bounds__(256) void k2_expert1(
    const float* __restrict__ Local, const float* __restrict__ Remote,
    const float* __restrict__ ae_w1, const float* __restrict__ ae_b1,
    float* __restrict__ ws)
{
    const int blk = blockIdx.x;
    const int track = blk >> 7;
    const int n0 = (blk & 127) * 64;
    const float* __restrict__ X = track ? Remote : Local;
    const float* __restrict__ om = ws + (track ? RO : LO);

    __shared__ __align__(16) float xsh[64 * 132];
    __shared__ __align__(16) float wsh[16 * 1040];
    __shared__ float omsh[64][8];
    __shared__ float b1sh[128];
    __shared__ float red[32];
    const int tid = threadIdx.x;

    for (int i = tid; i < 2048; i += 256) {
        int r = i >> 5, q = i & 31;
        ((float4*)&xsh[r * 132])[q] = ((const float4*)(X + (size_t)(n0 + r) * 132))[q];
    }
    for (int i4 = tid; i4 < 4096; i4 += 256) {
        float4 v = ((const float4*)ae_w1)[i4];
        int i = i4 * 4;
#pragma unroll
        for (int c = 0; c < 4; ++c) {
            int ii = i + c;
            int h = ii & 15, kk = (ii >> 4) & 127, e = ii >> 11;
            float vc = c == 0 ? v.x : c == 1 ? v.y : c == 2 ? v.z : v.w;
            wsh[h * 1040 + e * 130 + kk] = vc;
        }
    }
    for (int i = tid; i < 512; i += 256) omsh[i >> 3][i & 7] = om[(size_t)(n0 + (i >> 3)) * 8 + (i & 7)];
    for (int i = tid; i < 128; i += 256) b1sh[i] = ae_b1[i];
    if (tid < 32) red[tid] = 0.f;
    __syncthreads();

    const int hh = tid & 15, rg = tid >> 4;
    float acc[4][8];
#pragma unroll
    for (int r = 0; r < 4; ++r)
#pragma unroll
        for (int e = 0; e < 8; ++e) acc[r][e] = 0.f;

#pragma unroll 4
    for (int kq = 0; kq < 32; ++kq) {
        float4 xv[4], wv[8];
#pragma unroll
        for (int r = 0; r < 4; ++r) xv[r] = *(const float4*)&xsh[(rg * 4 + r) * 132 + kq * 4];
#pragma unroll
        for (int e = 0; e < 8; ++e) wv[e] = *(const float4*)&wsh[hh * 1040 + e * 130 + kq * 4];
#pragma unroll
        for (int r = 0; r < 4; ++r)
#pragma unroll
            for (int e = 0; e < 8; ++e) {
                float a = acc[r][e];
                a = fmaf(xv[r].x, wv[e].x, a);
                a = fmaf(xv[r].y, wv[e].y, a);
                a = fmaf(xv[r].z, wv[e].z, a);
                a = fmaf(xv[r].w, wv[e].w, a);
                acc[r][e] = a;
            }
    }

    float s = 0.f, s2 = 0.f;
    float* __restrict__ hout = ws + HBUF + (size_t)track * 131072;
#pragma unroll
    for (int r = 0; r < 4; ++r) {
        int row = rg * 4 + r;
        float hv = 0.f;
#pragma unroll
        for (int e = 0; e < 8; ++e) hv = fmaf(omsh[row][e], acc[r][e] + b1sh[e * 16 + hh], hv);
        hout[(size_t)(n0 + row) * 16 + hh] = hv;
        s += hv; s2 += hv * hv;
    }
    __syncthreads();
    atomicAdd(&red[hh], s);
    atomicAdd(&red[16 + hh], s2);
    __syncthreads();
    if (tid < 32) atomicAdd(&ws[ACC + track * 32 + tid], red[tid]);
}

// ===== K34: phase A (BN+ELU+MLP2+xw0) then phase B recurrence (wave 0) =====
__global__ __launch_bounds__(256, 1) void k34_fused(
    const float* __restrict__ ae_w2, const float* __restrict__ ae_b2,
    const float* __restrict__ ae_g, const float* __restrict__ ae_bt,
    const float* __restrict__ mWih0, const float* __restrict__ mbih0,
    const float* __restrict__ Whh0, const float* __restrict__ bhh0,
    const float* __restrict__ Wih1, const float* __restrict__ Whh1,
    const float* __restrict__ bih1, const float* __restrict__ bhh1,
    float* __restrict__ ws)
{
    const int s = blockIdx.x;           // sequence 0..63
    const int tid = threadIdx.x;

    __shared__ float stat[4][16];
    __shared__ float omsh[2][128][8];
    __shared__ float w2sh[2048];
    __shared__ float b2sh[128];
    __shared__ float actsh[2][128][16];
    __shared__ float zsh[128][17];
    __shared__ float wihsh[48][17];
    __shared__ float bihsh[48];
    __shared__ float xwsh[128 * 48];

    // ---- phase A ----
    if (tid < 32) {
        int trk = tid >> 4, h = tid & 15;
        float sm = ws[ACC + trk * 32 + h], s2 = ws[ACC + trk * 32 + 16 + h];
        float m = sm * (1.f / 8192.f);
        float v = fmaxf(s2 * (1.f / 8192.f) - m * m, 0.f);
        stat[trk * 2][h] = m;
        stat[trk * 2 + 1][h] = rsqrtf(v + 1e-5f);
    }
    for (int i = tid; i < 2048; i += 256) w2sh[i] = ae_w2[i];
    for (int i = tid; i < 128; i += 256) b2sh[i] = ae_b2[i];
    for (int i = tid; i < 768; i += 256) wihsh[i >> 4][i & 15] = mWih0[i];
    if (tid < 48) bihsh[tid] = mbih0[tid];
    for (int i = tid; i < 2048; i += 256) {
        int trk = i >> 10, r = (i >> 3) & 127, e = i & 7;
        omsh[trk][r][e] = ws[(trk ? RO : LO) + ((size_t)s * 128 + r) * 8 + e];
    }
    __syncthreads();

    for (int i = tid; i < 4096; i += 256) {
        int trk = i >> 11, r = (i >> 4) & 127, h = i & 15;
        float v = ws[HBUF + (size_t)trk * 131072 + ((size_t)s * 128 + r) * 16 + h];
        float a = ae_g[h] * (v - stat[trk * 2][h]) * stat[trk * 2 + 1][h] + ae_bt[h];
        actsh[trk][r][h] = a > 0.f ? a : expm1f(a);
    }
    __syncthreads();

    for (int i = tid; i < 2048; i += 256) {
        int r = i >> 4, o = i & 15;
        float accv = 0.f;
#pragma unroll
        for (int trk = 0; trk < 2; ++trk) {
#pragma unroll
            for (int e = 0; e < 8; ++e) {
                const float* w = &w2sh[e * 256 + o];
                float t = b2sh[e * 16 + o];
#pragma unroll
                for (int h = 0; h < 16; ++h) t = fmaf(actsh[trk][r][h], w[h * 16], t);
                accv = fmaf(omsh[trk][r][e], t, accv);
            }
        }
        zsh[r][o] = accv;
    }
    __syncthreads();

    for (int i = tid; i < 6144; i += 256) {
        int r = i / 48, g = i - r * 48;
        float a = bihsh[g];
#pragma unroll
        for (int k = 0; k < 16; ++k) a = fmaf(zsh[r][k], wihsh[g][k], a);
        xwsh[r * 48 + g] = a;
    }
    __syncthreads();

    // ---- phase B: recurrence, wave 0 only ----
    if (tid >= 64) return;

    const int j = tid & 15;
    const int layer = (tid >> 4) & 1;

    const float* __restrict__ Wsel = layer ? Wih1 : Whh0;
    const float mhi = layer ? 1.f : 0.f;
    const float m0f = layer ? 0.f : 1.f;

    // 96 named weight scalars
#define K34_WDECL(n) float wr##n, wz##n, wc##n, wrh##n, wzh##n, wch##n;
    K34_WDECL(0)  K34_WDECL(1)  K34_WDECL(2)  K34_WDECL(3)
    K34_WDECL(4)  K34_WDECL(5)  K34_WDECL(6)  K34_WDECL(7)
    K34_WDECL(8)  K34_WDECL(9)  K34_WDECL(10) K34_WDECL(11)
    K34_WDECL(12) K34_WDECL(13) K34_WDECL(14) K34_WDECL(15)
#undef K34_WDECL
#define K34_WINIT(n) \
    wr##n  = Wsel[j * 16 + (n)]; \
    wz##n  = Wsel[(16 + j) * 16 + (n)]; \
    wc##n  = Wsel[(32 + j) * 16 + (n)]; \
    wrh##n = mhi * Whh1[j * 16 + (n)]; \
    wzh##n = mhi * Whh1[(16 + j) * 16 + (n)]; \
    wch##n = mhi * Whh1[(32 + j) * 16 + (n)];
    K34_WINIT(0)  K34_WINIT(1)  K34_WINIT(2)  K34_WINIT(3)
    K34_WINIT(4)  K34_WINIT(5)  K34_WINIT(6)  K34_WINIT(7)
    K34_WINIT(8)  K34_WINIT(9)  K34_WINIT(10) K34_WINIT(11)
    K34_WINIT(12) K34_WINIT(13) K34_WINIT(14) K34_WINIT(15)
#undef K34_WINIT
#define K34_LND(n) LAUNDER4(wr##n, wz##n, wc##n, wrh##n); LAUNDER4(wzh##n, wch##n, wr##n, wz##n);
    K34_LND(0)  K34_LND(1)  K34_LND(2)  K34_LND(3)
    K34_LND(4)  K34_LND(5)  K34_LND(6)  K34_LND(7)
    K34_LND(8)  K34_LND(9)  K34_LND(10) K34_LND(11)
    K34_LND(12) K34_LND(13) K34_LND(14) K34_LND(15)
#undef K34_LND

    const float base_r  = layer ? (bih1[j] + bhh1[j])           : bhh0[j];
    const float base_z  = layer ? (bih1[16 + j] + bhh1[16 + j]) : bhh0[16 + j];
    const float base_in = layer ? bih1[32 + j]                  : 0.f;
    const float base_dn = layer ? bhh1[32 + j]                  : bhh0[32 + j];

    float hown = 0.f;
    float p0 = xwsh[j], p1 = xwsh[16 + j], p2 = xwsh[32 + j];
#pragma unroll 1
    for (int t = 0; t <= 128; ++t) {
        int tn = (t < 127 ? t + 1 : 127) * 48;
        float q0 = xwsh[tn + j], q1 = xwsh[tn + 16 + j], q2 = xwsh[tn + 32 + j];
        float arA = 0.f, arB = 0.f, azA = 0.f, azB = 0.f;
        float acl0 = 0.f, acl1 = 0.f, ach0 = 0.f, ach1 = 0.f;
#define K34_STEP(n, A, C) { \
        float b0 = readlanef(hown, (n)); \
        ar##A = fmaf(wr##n, b0, ar##A); \
        az##A = fmaf(wz##n, b0, az##A); \
        acl##C = fmaf(wc##n, b0, acl##C); \
        float b1 = readlanef(hown, 16 + (n)); \
        ar##A = fmaf(wrh##n, b1, ar##A); \
        az##A = fmaf(wzh##n, b1, az##A); \
        ach##C = fmaf(wch##n, b1, ach##C); }
        K34_STEP(0, A, 0)  K34_STEP(1, B, 1)
        K34_STEP(2, A, 0)  K34_STEP(3, B, 1)
        K34_STEP(4, A, 0)  K34_STEP(5, B, 1)
        K34_STEP(6, A, 0)  K34_STEP(7, B, 1)
        K34_STEP(8, A, 0)  K34_STEP(9, B, 1)
        K34_STEP(10, A, 0) K34_STEP(11, B, 1)
        K34_STEP(12, A, 0) K34_STEP(13, B, 1)
        K34_STEP(14, A, 0) K34_STEP(15, B, 1)
#undef K34_STEP
        float ac_lo = acl0 + acl1, ac_hi = ach0 + ach1;
        float ar = base_r + fmaf(m0f, p0, arA + arB);
        float az = base_z + fmaf(m0f, p1, azA + azB);
        float in_ = layer ? (base_in + ac_lo) : p2;
        float dn  = base_dn + (layer ? ac_hi : ac_lo);
        float r = fsig(ar);
        float z = fsig(az);
        float n = ftanh_(in_ + r * dn);
        float hnew = n + z * (hown - n);
        bool act = layer ? (t >= 1) : (t < 128);
        hown = act ? hnew : hown;
        p0 = q0; p1 = q1; p2 = q2;
    }
    if (tid >= 16 && tid < 32) ws[ZLAST + (size_t)s * 16 + j] = hown;
}

// ===== K5: decoder MLP fused (layer1+BN redundant per block, layer2 slice) =====
__global__ __launch_bounds__(256) void k5_dec(
    const float* __restrict__ Remote,
    const float* __restrict__ md_w1, const float* __restrict__ md_b1,
    const float* __restrict__ md_g, const float* __restrict__ md_bt,
    const float* __restrict__ md_w2, const float* __restrict__ md_b2,
    const float* __restrict__ ws, float* __restrict__ out)
{
    const int o0 = blockIdx.x * 8;
    const int tid = threadIdx.x;
    __shared__ float xsh[64][17];
    __shared__ float omsh[64][8];
    __shared__ float w1sh[2176];
    __shared__ float b1sh[128];
    __shared__ float hsh[64][17];
    __shared__ float ssum[16], ss2[16], mstat[2][16];
    __shared__ float ash[64][17];
    __shared__ float w2sh[8][16][8];
    __shared__ float b2sh[8][8];

    for (int i = tid; i < 1024; i += 256) xsh[i >> 4][i & 15] = ws[ZLAST + i];
    if (tid < 64) xsh[tid][16] = Remote[((size_t)tid * 128 + 127) * 132 + 131];
    for (int i = tid; i < 512; i += 256)
        omsh[i >> 3][i & 7] = ws[RO + ((size_t)(i >> 3) * 128 + 127) * 8 + (i & 7)];
    for (int i = tid; i < 2176; i += 256) w1sh[i] = md_w1[i];
    for (int i = tid; i < 128; i += 256) b1sh[i] = md_b1[i];
    for (int i = tid; i < 1024; i += 256) {
        int e = i >> 7, h = (i >> 3) & 15, oo = i & 7;
        w2sh[e][h][oo] = md_w2[((size_t)e * 16 + h) * 128 + o0 + oo];
    }
    if (tid < 64) b2sh[tid >> 3][tid & 7] = md_b2[(size_t)(tid >> 3) * 128 + o0 + (tid & 7)];
    if (tid < 16) { ssum[tid] = 0.f; ss2[tid] = 0.f; }
    __syncthreads();

    for (int i = tid; i < 1024; i += 256) {
        int b = i >> 4, h = i & 15;
        float accv = 0.f;
#pragma unroll
        for (int e = 0; e < 8; ++e) {
            float t = b1sh[e * 16 + h];
            const float* w = &w1sh[e * 272 + h];
#pragma unroll
            for (int i2 = 0; i2 < 17; ++i2) t = fmaf(xsh[b][i2], w[i2 * 16], t);
            accv = fmaf(omsh[b][e], t, accv);
        }
        hsh[b][h] = accv;
        atomicAdd(&ssum[h], accv);
        atomicAdd(&ss2[h], accv * accv);
    }
    __syncthreads();
    if (tid < 16) {
        float m = ssum[tid] * (1.f / 64.f);
        float v = fmaxf(ss2[tid] * (1.f / 64.f) - m * m, 0.f);
        mstat[0][tid] = m;
        mstat[1][tid] = rsqrtf(v + 1e-5f);
    }
    __syncthreads();
    for (int i = tid; i < 1024; i += 256) {
        int b = i >> 4, h = i & 15;
        float a = md_g[h] * (hsh[b][h] - mstat[0][h]) * mstat[1][h] + md_bt[h];
        ash[b][h] = a > 0.f ? a : expm1f(a);
    }
    __syncthreads();

    for (int i = tid; i < 512; i += 256) {
        int b = i >> 3, oo = i & 7;
        float accv = 0.f;
#pragma unroll
        for (int e = 0; e < 8; ++e) {
            float t = b2sh[e][oo];
#pragma unroll
            for (int h = 0; h < 16; ++h) t = fmaf(ash[b][h], w2sh[e][h][oo], t);
            accv = fmaf(omsh[b][e], t, accv);
        }
        out[(size_t)b * 128 + o0 + oo] = accv;
    }
}

extern "C" void kernel_launch(void* const* d_in, const int* in_sizes, int n_in,
                              void* d_out, int out_size, void* d_ws, size_t ws_size,
                              hipStream_t stream) {
    const float* Local  = (const float*)d_in[0];
    const float* Remote = (const float*)d_in[1];
    const float* gWih0  = (const float*)d_in[2];
    const float* gWhh0  = (const float*)d_in[3];
    const float* gbih0  = (const float*)d_in[4];
    const float* gbhh0  = (const float*)d_in[5];
    const float* gWih1  = (const float*)d_in[6];
    const float* gWhh1  = (const float*)d_in[7];
    const float* gbih1  = (const float*)d_in[8];
    const float* gbhh1  = (const float*)d_in[9];
    const float* mWih0  = (const float*)d_in[10];
    const float* mWhh0  = (const float*)d_in[11];
    const float* mbih0  = (const float*)d_in[12];
    const float* mbhh0  = (const float*)d_in[13];
    const float* mWih1  = (const float*)d_in[14];
    const float* mWhh1  = (const float*)d_in[15];
    const float* mbih1  = (const float*)d_in[16];
    const float* mbhh1  = (const float*)d_in[17];
    const float* ae_w1  = (const float*)d_in[18];
    const float* ae_b1  = (const float*)d_in[19];
    const float* ae_w2  = (const float*)d_in[20];
    const float* ae_b2  = (const float*)d_in[21];
    const float* ae_g   = (const float*)d_in[22];
    const float* ae_bt  = (const float*)d_in[23];
    const float* md_w1  = (const float*)d_in[24];
    const float* md_b1  = (const float*)d_in[25];
    const float* md_w2  = (const float*)d_in[26];
    const float* md_b2  = (const float*)d_in[27];
    const float* md_g   = (const float*)d_in[28];
    const float* md_bt  = (const float*)d_in[29];
    float* ws  = (float*)d_ws;
    float* out = (float*)d_out;

    k1_gate<<<128, 64, 0, stream>>>(Local, Remote, gWih0, gWhh0, gbih0, gbhh0,
                                    gWih1, gWhh1, gbih1, gbhh1, ws);
    k2_expert1<<<256, 256, 0, stream>>>(Local, Remote, ae_w1, ae_b1, ws);
    k34_fused<<<64, 256, 0, stream>>>(ae_w2, ae_b2, ae_g, ae_bt, mWih0, mbih0,
                                      mWhh0, mbhh0, mWih1, mWhh1, mbih1, mbhh1, ws);
    k5_dec<<<16, 256, 0, stream>>>(Remote, md_w1, md_b1, md_g, md_bt,
                                   md_w2, md_b2, ws, out);
}